// Round 3
// baseline (88.320 us; speedup 1.0000x reference)
//
#include <hip/hip_runtime.h>
#include <math.h>

#define BB 512
#define CC 256
typedef unsigned long long u64;

__device__ inline float wave_sum(float v) {
    #pragma unroll
    for (int off = 32; off > 0; off >>= 1) v += __shfl_down(v, off, 64);
    return v;
}
__device__ inline float wave_max(float v) {
    #pragma unroll
    for (int off = 32; off > 0; off >>= 1) v = fmaxf(v, __shfl_down(v, off, 64));
    return v;
}

// ---------------- Kernel 1: pack bit-planes + full masked-BCE accumulation ---
// 16 blocks x 512 threads. Block b owns rows [32b, 32b+32). Wave w packs rows
// 32b+4w .. +3, 4 ballot-chunks of 64 concepts each. The same mc load feeds
// both the ballot and the BCE mask, so mc is read exactly once.
// bitsP layout: bitsP[c*BB + r] (plane-major -> K2's per-j loads coalesce).
__global__ __launch_bounds__(512) void pack_bce_kernel(
        const int* __restrict__ mc, const float* __restrict__ cl,
        u64* __restrict__ bitsP, float* __restrict__ accBM) {
    int b = blockIdx.x, tid = threadIdx.x;
    int wave = tid >> 6, lane = tid & 63;

    float bsum = 0.0f, msum = 0.0f;
    #pragma unroll
    for (int rr = 0; rr < 4; ++rr) {
        int r = b * 32 + wave * 4 + rr;
        #pragma unroll
        for (int c = 0; c < 4; ++c) {
            int idx = r * CC + c * 64 + lane;
            int cv = mc[idx];
            u64 bal = __ballot(cv == 1);
            if (lane == 0) bitsP[c * BB + r] = bal;
            float x = cl[idx];
            float mask = (cv != -1) ? 1.0f : 0.0f;
            float t = (cv == 1) ? 1.0f : 0.0f;
            bsum += (fmaxf(x, 0.0f) - x * t + log1pf(__expf(-fabsf(x)))) * mask;
            msum += mask;
        }
    }
    __shared__ float red[8][2];
    float wb = wave_sum(bsum), wm = wave_sum(msum);
    if (lane == 0) { red[wave][0] = wb; red[wave][1] = wm; }
    __syncthreads();
    if (tid == 0) {
        float B = 0.0f, M = 0.0f;
        #pragma unroll
        for (int w = 0; w < 8; ++w) { B += red[w][0]; M += red[w][1]; }
        atomicAdd(&accBM[0], B);
        atomicAdd(&accBM[1], M);
    }
}

// ---------------- Kernel 2: one block per row; atomic accumulate into out ----
__global__ __launch_bounds__(512) void row_kernel(
        const float* __restrict__ lpi, const float* __restrict__ lpt,
        const float* __restrict__ cis, const u64* __restrict__ bitsP,
        const float* __restrict__ accBM, float* __restrict__ out) {
    int i = blockIdx.x, tid = threadIdx.x;
    int wave = tid >> 6, lane = tid & 63;
    __shared__ float red[8][8];

    // own-row masks (uniform address -> scalar loads)
    u64 m0 = bitsP[0 * BB + i], m1 = bitsP[1 * BB + i];
    u64 m2 = bitsP[2 * BB + i], m3 = bitsP[3 * BB + i];

    int j = tid;
    u64 b0 = bitsP[0 * BB + j], b1 = bitsP[1 * BB + j];
    u64 b2 = bitsP[2 * BB + j], b3 = bitsP[3 * BB + j];
    int inter = __popcll(m0 & b0) + __popcll(m1 & b1) + __popcll(m2 & b2) + __popcll(m3 & b3);
    int uni   = __popcll(m0 | b0) + __popcll(m1 | b1) + __popcll(m2 | b2) + __popcll(m3 | b3);
    float a = (uni > 0) ? (5.0f * (float)inter / (float)uni) : 0.0f;  // sim/T

    size_t off = (size_t)i * BB + j;
    float x0 = lpi[off], x1 = lpt[off], x2 = cis[off];

    // ---- phase 1: 4 independent maxes, one barrier ----
    float mv[4] = { a, x0, x1, x2 };
    #pragma unroll
    for (int k = 0; k < 4; ++k) {
        float w = wave_max(mv[k]);
        if (lane == 0) red[wave][k] = w;
    }
    __syncthreads();
    float M[4];
    #pragma unroll
    for (int k = 0; k < 4; ++k) {
        float m = red[0][k];
        #pragma unroll
        for (int w = 1; w < 8; ++w) m = fmaxf(m, red[w][k]);
        M[k] = m;
    }
    __syncthreads();   // red reuse

    // ---- phase 2: 8 independent sums, one barrier ----
    float e = __expf(a - M[0]);
    float sv[8] = { e, e * a,
                    __expf(x0 - M[1]), e * x0,
                    __expf(x1 - M[2]), e * x1,
                    __expf(x2 - M[3]), e * x2 };
    #pragma unroll
    for (int k = 0; k < 8; ++k) {
        float w = wave_sum(sv[k]);
        if (lane == 0) red[wave][k] = w;
    }
    __syncthreads();

    if (tid == 0) {
        float S[8];
        #pragma unroll
        for (int k = 0; k < 8; ++k) {
            float s = red[0][k];
            #pragma unroll
            for (int w = 1; w < 8; ++w) s += red[w][k];
            S[k] = s;
        }
        float Z = S[0], invZ = 1.0f / Z, lZ = logf(Z);
        float ent = S[1] * invZ - M[0] - lZ;              // sum t*log t
        float ci  = S[3] * invZ - M[1] - logf(S[2]);      // sum t*log_softmax(lpi)
        float ct  = S[5] * invZ - M[2] - logf(S[4]);
        float cc  = S[7] * invZ - M[3] - logf(S[6]);
        float ctr = (2.0f * ent - ci - ct) * (0.5f / (float)BB)
                  + 0.2f * (ent - cc) * (1.0f / (float)BB);
        // K1's atomics are visible here (kernel dispatch boundary).
        if (i == 0) ctr += 0.2f * (accBM[0] / (accBM[1] + 1e-8f));
        atomicAdd(out, ctr);
    }
}

extern "C" void kernel_launch(void* const* d_in, const int* in_sizes, int n_in,
                              void* d_out, int out_size, void* d_ws, size_t ws_size,
                              hipStream_t stream) {
    const float* lpi = (const float*)d_in[0];   // logits_per_image [512,512]
    const float* lpt = (const float*)d_in[1];   // logits_per_text  [512,512]
    const float* cl  = (const float*)d_in[2];   // concepts_logits  [512,256]
    const float* cis = (const float*)d_in[3];   // concepts_image_similarity [512,512]
    const int*   mc  = (const int*)d_in[4];     // medical_concepts [512,256]

    char* ws = (char*)d_ws;
    u64*   bitsP = (u64*)ws;                     // 4*512*8 = 16384 B
    float* accBM = (float*)(ws + 16384);         // 2 floats

    float* out = (float*)d_out;

    hipMemsetAsync(accBM, 0, 2 * sizeof(float), stream);
    hipMemsetAsync(out, 0, sizeof(float), stream);
    pack_bce_kernel<<<16, 512, 0, stream>>>(mc, cl, bitsP, accBM);
    row_kernel<<<BB, 512, 0, stream>>>(lpi, lpt, cis, bitsP, accBM, out);
}

// Round 4
// 81.550 us; speedup vs baseline: 1.0830x; 1.0830x over previous
//
#include <hip/hip_runtime.h>
#include <math.h>

#define BB 512
#define CC 256
typedef unsigned long long u64;

__device__ inline float wave_sum(float v) {
    #pragma unroll
    for (int off = 32; off > 0; off >>= 1) v += __shfl_down(v, off, 64);
    return v;
}
__device__ inline float wave_max(float v) {
    #pragma unroll
    for (int off = 32; off > 0; off >>= 1) v = fmaxf(v, __shfl_down(v, off, 64));
    return v;
}

// ---------------- Kernel 1: pack concept bit-planes + BCE partials -----------
// 16 blocks x 512 threads. Block b owns rows [32b, 32b+32). One mc load feeds
// both the ballot-pack and the BCE mask. Plain stores only; visibility to K2/K3
// is via the kernel dispatch boundary (implicit acquire/release) — measured:
// fences (R2, +8us) and device atomics (R3, +7us) are both slower than this.
// bitsP layout: bitsP[c*BB + r] (plane-major -> K2's per-j loads coalesce).
__global__ __launch_bounds__(512) void pack_bce_kernel(
        const int* __restrict__ mc, const float* __restrict__ cl,
        u64* __restrict__ bitsP, float* __restrict__ bceP, float* __restrict__ mskP) {
    int b = blockIdx.x, tid = threadIdx.x;
    int wave = tid >> 6, lane = tid & 63;

    float bsum = 0.0f, msum = 0.0f;
    #pragma unroll
    for (int rr = 0; rr < 4; ++rr) {
        int r = b * 32 + wave * 4 + rr;
        #pragma unroll
        for (int c = 0; c < 4; ++c) {
            int idx = r * CC + c * 64 + lane;
            int cv = mc[idx];
            u64 bal = __ballot(cv == 1);
            if (lane == 0) bitsP[c * BB + r] = bal;
            float x = cl[idx];
            float mask = (cv != -1) ? 1.0f : 0.0f;
            float t = (cv == 1) ? 1.0f : 0.0f;
            bsum += (fmaxf(x, 0.0f) - x * t + log1pf(__expf(-fabsf(x)))) * mask;
            msum += mask;
        }
    }
    __shared__ float red[8][2];
    float wb = wave_sum(bsum), wm = wave_sum(msum);
    if (lane == 0) { red[wave][0] = wb; red[wave][1] = wm; }
    __syncthreads();
    if (tid == 0) {
        float B = 0.0f, M = 0.0f;
        #pragma unroll
        for (int w = 0; w < 8; ++w) { B += red[w][0]; M += red[w][1]; }
        bceP[b] = B;
        mskP[b] = M;
    }
}

// ---------------- Kernel 2: one block per row -> one scalar per row ----------
__global__ __launch_bounds__(512) void row_kernel(
        const float* __restrict__ lpi, const float* __restrict__ lpt,
        const float* __restrict__ cis, const u64* __restrict__ bitsP,
        float* __restrict__ contrib) {
    int i = blockIdx.x, tid = threadIdx.x;
    int wave = tid >> 6, lane = tid & 63;
    __shared__ float red[8][8];

    // own-row masks (uniform address -> scalar loads)
    u64 m0 = bitsP[0 * BB + i], m1 = bitsP[1 * BB + i];
    u64 m2 = bitsP[2 * BB + i], m3 = bitsP[3 * BB + i];

    int j = tid;
    u64 b0 = bitsP[0 * BB + j], b1 = bitsP[1 * BB + j];
    u64 b2 = bitsP[2 * BB + j], b3 = bitsP[3 * BB + j];
    int inter = __popcll(m0 & b0) + __popcll(m1 & b1) + __popcll(m2 & b2) + __popcll(m3 & b3);
    int uni   = __popcll(m0 | b0) + __popcll(m1 | b1) + __popcll(m2 | b2) + __popcll(m3 | b3);
    float a = (uni > 0) ? (5.0f * (float)inter / (float)uni) : 0.0f;  // sim/T

    size_t off = (size_t)i * BB + j;
    float x0 = lpi[off], x1 = lpt[off], x2 = cis[off];

    // ---- phase 1: 4 independent maxes, one barrier ----
    float mv[4] = { a, x0, x1, x2 };
    #pragma unroll
    for (int k = 0; k < 4; ++k) {
        float w = wave_max(mv[k]);
        if (lane == 0) red[wave][k] = w;
    }
    __syncthreads();
    float M[4];
    #pragma unroll
    for (int k = 0; k < 4; ++k) {
        float m = red[0][k];
        #pragma unroll
        for (int w = 1; w < 8; ++w) m = fmaxf(m, red[w][k]);
        M[k] = m;
    }
    __syncthreads();   // red reuse

    // ---- phase 2: 8 independent sums, one barrier ----
    float e = __expf(a - M[0]);
    float sv[8] = { e, e * a,
                    __expf(x0 - M[1]), e * x0,
                    __expf(x1 - M[2]), e * x1,
                    __expf(x2 - M[3]), e * x2 };
    #pragma unroll
    for (int k = 0; k < 8; ++k) {
        float w = wave_sum(sv[k]);
        if (lane == 0) red[wave][k] = w;
    }
    __syncthreads();

    if (tid == 0) {
        float S[8];
        #pragma unroll
        for (int k = 0; k < 8; ++k) {
            float s = red[0][k];
            #pragma unroll
            for (int w = 1; w < 8; ++w) s += red[w][k];
            S[k] = s;
        }
        float Z = S[0], invZ = 1.0f / Z, lZ = logf(Z);
        float ent = S[1] * invZ - M[0] - lZ;              // sum t*log t
        float ci  = S[3] * invZ - M[1] - logf(S[2]);      // sum t*log_softmax(lpi)
        float ct  = S[5] * invZ - M[2] - logf(S[4]);
        float cc  = S[7] * invZ - M[3] - logf(S[6]);
        contrib[i] = (2.0f * ent - ci - ct) * (0.5f / (float)BB)
                   + 0.2f * (ent - cc) * (1.0f / (float)BB);
    }
}

// ---------------- Kernel 3: final reduction + combine ------------------------
__global__ __launch_bounds__(512) void finalize_kernel(
        const float* __restrict__ contrib, const float* __restrict__ bceP,
        const float* __restrict__ mskP, float* __restrict__ out) {
    int tid = threadIdx.x;
    int wave = tid >> 6, lane = tid & 63;
    float c = contrib[tid];
    float b = (tid < 16) ? bceP[tid] : 0.0f;
    float m = (tid < 16) ? mskP[tid] : 0.0f;
    __shared__ float red[8][3];
    float wc = wave_sum(c), wb = wave_sum(b), wm = wave_sum(m);
    if (lane == 0) { red[wave][0] = wc; red[wave][1] = wb; red[wave][2] = wm; }
    __syncthreads();
    if (tid == 0) {
        float C = 0.0f, Bs = 0.0f, Ms = 0.0f;
        #pragma unroll
        for (int w = 0; w < 8; ++w) { C += red[w][0]; Bs += red[w][1]; Ms += red[w][2]; }
        out[0] = C + 0.2f * (Bs / (Ms + 1e-8f));
    }
}

extern "C" void kernel_launch(void* const* d_in, const int* in_sizes, int n_in,
                              void* d_out, int out_size, void* d_ws, size_t ws_size,
                              hipStream_t stream) {
    const float* lpi = (const float*)d_in[0];   // logits_per_image [512,512]
    const float* lpt = (const float*)d_in[1];   // logits_per_text  [512,512]
    const float* cl  = (const float*)d_in[2];   // concepts_logits  [512,256]
    const float* cis = (const float*)d_in[3];   // concepts_image_similarity [512,512]
    const int*   mc  = (const int*)d_in[4];     // medical_concepts [512,256]

    char* ws = (char*)d_ws;
    u64*   bitsP   = (u64*)ws;                   // 4*512*8 = 16384 B
    float* bceP    = (float*)(ws + 16384);       // 16 floats
    float* mskP    = bceP + 16;                  // 16 floats
    float* contrib = mskP + 16;                  // 512 floats

    float* out = (float*)d_out;

    pack_bce_kernel<<<16, 512, 0, stream>>>(mc, cl, bitsP, bceP, mskP);
    row_kernel<<<BB, 512, 0, stream>>>(lpi, lpt, cis, bitsP, contrib);
    finalize_kernel<<<1, 512, 0, stream>>>(contrib, bceP, mskP, out);
}

// Round 5
// 69.603 us; speedup vs baseline: 1.2689x; 1.1716x over previous
//
#include <hip/hip_runtime.h>
#include <math.h>

#define BB 512
#define CC 256
typedef unsigned long long u64;

__device__ inline float wave_sum(float v) {
    #pragma unroll
    for (int off = 32; off > 0; off >>= 1) v += __shfl_down(v, off, 64);
    return v;
}
__device__ inline float wave_max(float v) {
    #pragma unroll
    for (int off = 32; off > 0; off >>= 1) v = fmaxf(v, __shfl_down(v, off, 64));
    return v;
}

// ---------------- Kernel 1: pack bit-planes + per-row BCE partials -----------
// R1 geometry (best measured: 73.7us total): 512 blocks x 256 threads — full
// chip coverage for the 1 MB mc+cl read. One mc load feeds both the
// ballot-pack and the BCE mask. Plain stores only; visibility to K2/K3 via
// kernel dispatch boundaries (fences: +8us R2; device atomics: +7us R3).
// bitsP layout: bitsP[c*BB + r] (plane-major -> K2's per-j loads coalesce).
__global__ __launch_bounds__(256) void pack_bce_kernel(
        const int* __restrict__ mc, const float* __restrict__ cl,
        u64* __restrict__ bitsP, float* __restrict__ bceP, float* __restrict__ mskP) {
    int i = blockIdx.x, tid = threadIdx.x;
    int wave = tid >> 6, lane = tid & 63;

    int c = mc[i * CC + tid];
    u64 bal = __ballot(c == 1);
    if (lane == 0) bitsP[wave * BB + i] = bal;

    float x = cl[i * CC + tid];
    float mask = (c != -1) ? 1.0f : 0.0f;
    float t = (c == 1) ? 1.0f : 0.0f;
    float bce = (fmaxf(x, 0.0f) - x * t + log1pf(__expf(-fabsf(x)))) * mask;

    __shared__ float red[4][2];
    float wb = wave_sum(bce), wm = wave_sum(mask);
    if (lane == 0) { red[wave][0] = wb; red[wave][1] = wm; }
    __syncthreads();
    if (tid == 0) {
        bceP[i] = red[0][0] + red[1][0] + red[2][0] + red[3][0];
        mskP[i] = red[0][1] + red[1][1] + red[2][1] + red[3][1];
    }
}

// ---------------- Kernel 2: one block per row (256 thr x 2 cols) -------------
// R1 geometry, minus the a[512] LDS staging (sim held in registers), with the
// 12 sequential block reductions batched into 2 phases (~5 barriers vs 24).
__global__ __launch_bounds__(256) void row_kernel(
        const float* __restrict__ lpi, const float* __restrict__ lpt,
        const float* __restrict__ cis, const u64* __restrict__ bitsP,
        float* __restrict__ contrib) {
    int i = blockIdx.x, tid = threadIdx.x;
    int wave = tid >> 6, lane = tid & 63;
    __shared__ float red[4][8];

    // own-row masks (uniform address -> scalar loads)
    u64 m0 = bitsP[0 * BB + i], m1 = bitsP[1 * BB + i];
    u64 m2 = bitsP[2 * BB + i], m3 = bitsP[3 * BB + i];

    float a[2];
    #pragma unroll
    for (int jj = 0; jj < 2; ++jj) {
        int j = tid + jj * 256;
        u64 b0 = bitsP[0 * BB + j], b1 = bitsP[1 * BB + j];
        u64 b2 = bitsP[2 * BB + j], b3 = bitsP[3 * BB + j];
        int inter = __popcll(m0 & b0) + __popcll(m1 & b1) + __popcll(m2 & b2) + __popcll(m3 & b3);
        int uni   = __popcll(m0 | b0) + __popcll(m1 | b1) + __popcll(m2 | b2) + __popcll(m3 | b3);
        a[jj] = (uni > 0) ? (5.0f * (float)inter / (float)uni) : 0.0f;  // sim/T
    }

    size_t off = (size_t)i * BB + tid;
    float x00 = lpi[off], x01 = lpi[off + 256];
    float x10 = lpt[off], x11 = lpt[off + 256];
    float x20 = cis[off], x21 = cis[off + 256];

    // ---- phase 1: 4 independent maxes, one barrier pair ----
    float mv[4] = { fmaxf(a[0], a[1]), fmaxf(x00, x01), fmaxf(x10, x11), fmaxf(x20, x21) };
    #pragma unroll
    for (int k = 0; k < 4; ++k) {
        float w = wave_max(mv[k]);
        if (lane == 0) red[wave][k] = w;
    }
    __syncthreads();
    float M[4];
    #pragma unroll
    for (int k = 0; k < 4; ++k)
        M[k] = fmaxf(fmaxf(red[0][k], red[1][k]), fmaxf(red[2][k], red[3][k]));
    __syncthreads();   // red reuse

    // ---- phase 2: 8 independent sums, one barrier pair ----
    float e0 = __expf(a[0] - M[0]), e1 = __expf(a[1] - M[0]);
    float sv[8] = { e0 + e1, e0 * a[0] + e1 * a[1],
                    __expf(x00 - M[1]) + __expf(x01 - M[1]), e0 * x00 + e1 * x01,
                    __expf(x10 - M[2]) + __expf(x11 - M[2]), e0 * x10 + e1 * x11,
                    __expf(x20 - M[3]) + __expf(x21 - M[3]), e0 * x20 + e1 * x21 };
    #pragma unroll
    for (int k = 0; k < 8; ++k) {
        float w = wave_sum(sv[k]);
        if (lane == 0) red[wave][k] = w;
    }
    __syncthreads();

    if (tid == 0) {
        float S[8];
        #pragma unroll
        for (int k = 0; k < 8; ++k)
            S[k] = red[0][k] + red[1][k] + red[2][k] + red[3][k];
        float Z = S[0], invZ = 1.0f / Z, lZ = logf(Z);
        float ent = S[1] * invZ - M[0] - lZ;              // sum t*log t
        float ci  = S[3] * invZ - M[1] - logf(S[2]);      // sum t*log_softmax(lpi)
        float ct  = S[5] * invZ - M[2] - logf(S[4]);
        float cc  = S[7] * invZ - M[3] - logf(S[6]);
        contrib[i] = (2.0f * ent - ci - ct) * (0.5f / (float)BB)
                   + 0.2f * (ent - cc) * (1.0f / (float)BB);
    }
}

// ---------------- Kernel 3: final reduction + combine ------------------------
__global__ __launch_bounds__(512) void finalize_kernel(
        const float* __restrict__ contrib, const float* __restrict__ bceP,
        const float* __restrict__ mskP, float* __restrict__ out) {
    int tid = threadIdx.x;
    int wave = tid >> 6, lane = tid & 63;
    float c = contrib[tid];
    float b = bceP[tid];
    float m = mskP[tid];
    __shared__ float red[8][3];
    float wc = wave_sum(c), wb = wave_sum(b), wm = wave_sum(m);
    if (lane == 0) { red[wave][0] = wc; red[wave][1] = wb; red[wave][2] = wm; }
    __syncthreads();
    if (tid == 0) {
        float C = 0.0f, Bs = 0.0f, Ms = 0.0f;
        #pragma unroll
        for (int w = 0; w < 8; ++w) { C += red[w][0]; Bs += red[w][1]; Ms += red[w][2]; }
        out[0] = C + 0.2f * (Bs / (Ms + 1e-8f));
    }
}

extern "C" void kernel_launch(void* const* d_in, const int* in_sizes, int n_in,
                              void* d_out, int out_size, void* d_ws, size_t ws_size,
                              hipStream_t stream) {
    const float* lpi = (const float*)d_in[0];   // logits_per_image [512,512]
    const float* lpt = (const float*)d_in[1];   // logits_per_text  [512,512]
    const float* cl  = (const float*)d_in[2];   // concepts_logits  [512,256]
    const float* cis = (const float*)d_in[3];   // concepts_image_similarity [512,512]
    const int*   mc  = (const int*)d_in[4];     // medical_concepts [512,256]

    char* ws = (char*)d_ws;
    u64*   bitsP   = (u64*)ws;                   // 4*512*8 = 16384 B
    float* bceP    = (float*)(ws + 16384);       // 512 floats
    float* mskP    = bceP + BB;                  // 512 floats
    float* contrib = mskP + BB;                  // 512 floats

    float* out = (float*)d_out;

    pack_bce_kernel<<<BB, CC, 0, stream>>>(mc, cl, bitsP, bceP, mskP);
    row_kernel<<<BB, CC, 0, stream>>>(lpi, lpt, cis, bitsP, contrib);
    finalize_kernel<<<1, BB, 0, stream>>>(contrib, bceP, mskP, out);
}